// Round 5
// baseline (506.842 us; speedup 1.0000x reference)
//
#include <hip/hip_runtime.h>
#include <stdint.h>

// CPRLinear: out = x[:, ci] @ dequant(W).T + bias
// B=256, IN=OUT=8192; W_high (8192x2048 int32, tile 128), W_low (8192x6144).
// R4 post-mortem: spill (LB(256,4) + 140 regs) -> 243MB scratch writes.
// R2/R3 model: steps self-clock at load latency (~4000cy) with 1-step prefetch.
// R5: W staged RAW int32 via global_load_lds, 4-deep LDS pipeline (zero VGPR),
// dequant fused into LDS->reg read feeding MFMA. BN=32 (acc=32 regs), 3
// blocks/CU, counted vmcnt(1) keeps prefetch in flight across the barrier.

#define IN_DIM 8192
#define OUT_DIM 8192
#define BDIM 256
#define NH 2048
#define NL 6144
#define BN 32
#define BK 32
#define KSPLIT 4
#define KSEG 2048          // IN_DIM / KSPLIT
#define NSTEP 64           // KSEG / BK
#define NT 16              // scale tiles per segment (KSEG/128)

// LDS layout (52KB):
//   X dbuf: 2 x 16384 @ 0       ([256 rows][32 k] bf16, chunk^(row&3) swz)
//   W 4-deep: 4 x 4096 @ 32768  ([32 cols][32 k] int32, chunk^(col&7) swz)
//   SC @ 49152, ZS @ 51200      ([16 tiles][32 cols] f32; zs = z*s)
#define XOFF 0
#define WOFF 32768
#define SCOFF 49152
#define ZSOFF 51200

typedef __bf16 bf16x8 __attribute__((ext_vector_type(8)));
typedef float f32x4 __attribute__((ext_vector_type(4)));

__device__ __forceinline__ unsigned short bfbits(float f) {
  union { float f; unsigned int u; } v; v.f = f;
  unsigned int u = v.u;
  u += 0x7fffu + ((u >> 16) & 1u);   // RNE
  return (unsigned short)(u >> 16);
}
__device__ __forceinline__ unsigned int pk2(float a, float b) {
  return (unsigned int)bfbits(a) | ((unsigned int)bfbits(b) << 16);
}

// ---------------- gather + bf16 convert: xp[b][k] = bf16(x[b][ci[k]]) ------
__global__ void gather_k(const float* __restrict__ x,
                         const int* __restrict__ ci,
                         unsigned short* __restrict__ xp) {
  int i4 = blockIdx.x * blockDim.x + threadIdx.x;   // 0..524287
  int b = i4 >> 11;                                  // row (2048 quads/row)
  int k4 = (i4 & 2047) << 2;
  int4 c = *(const int4*)(ci + k4);
  const float* xr = x + (size_t)b * IN_DIM;
  uint2 st;
  st.x = pk2(xr[c.x], xr[c.y]);
  st.y = pk2(xr[c.z], xr[c.w]);
  *(uint2*)(xp + (size_t)b * IN_DIM + k4) = st;
}

// ---------------- GEMM ----------------------------------------------------
// Grid 1024 linear; bijective XCD swizzle -> (kh, n-block). Block 256 thr =
// 4 waves; wave wv: rows wv*64..+63 x cols n0..n0+31. acc[4][2] (32 VGPR).
__global__ __launch_bounds__(256, 3)
void gemm_k(const unsigned short* __restrict__ xp,
            const int* __restrict__ Whq, const int* __restrict__ Wlq,
            const float* __restrict__ sh, const float* __restrict__ zh,
            const float* __restrict__ sl, const float* __restrict__ zl,
            const float* __restrict__ bias,
            float* __restrict__ outp,
            int use_atomic)
{
  __shared__ char smem[53248];
  const int t = threadIdx.x;
  const int lane = t & 63;
  const int wv = t >> 6;
  const int l15 = lane & 15;
  const int g4 = lane >> 4;

  // XCD-bijective swizzle (nwg=1024 % 8 == 0): XCD x gets swz [x*128,(x+1)*128)
  // kh-major decode -> each XCD covers one kh's x-slice (1MB, L2-resident).
  const int swz = (blockIdx.x & 7) * 128 + (blockIdx.x >> 3);
  const int kh = swz >> 8;          // 0..3
  const int n0 = (swz & 255) * BN;  // 0..8160
  const bool hi = (kh == 0);        // KSEG==NH: kh0 = all-high, else all-low

  // X staging: thread t -> row=t>>2 (+64/round), src chunk=(t&3)^(row&3)
  const int xrow = t >> 2;
  const unsigned short* xsrc0 = xp + (size_t)xrow * IN_DIM + (size_t)kh * KSEG
                                   + ((t & 3) ^ (xrow & 3)) * 8;
  // W staging: thread t -> col=t>>3 (0..31), src chunk=(t&7)^(col&7), 16B
  const int wcol = t >> 3;
  const int* wsrc0 = (hi ? Whq + (size_t)(n0 + wcol) * NH
                         : Wlq + (size_t)(n0 + wcol) * NL + (size_t)(kh - 1) * KSEG)
                     + ((t & 7) ^ (wcol & 7)) * 4;

  const float* sb = (hi ? sh : sl + (size_t)(kh - 1) * NT * OUT_DIM) + n0;
  const float* zb = (hi ? zh : zl + (size_t)(kh - 1) * NT * OUT_DIM) + n0;

  f32x4 acc[4][2];
  {
    float bv0 = hi ? bias[n0 + l15] : 0.f;
    float bv1 = hi ? bias[n0 + 16 + l15] : 0.f;
    #pragma unroll
    for (int i = 0; i < 4; ++i) {
      acc[i][0][0] = bv0; acc[i][0][1] = bv0; acc[i][0][2] = bv0; acc[i][0][3] = bv0;
      acc[i][1][0] = bv1; acc[i][1][1] = bv1; acc[i][1][2] = bv1; acc[i][1][3] = bv1;
    }
  }

  auto stage_x = [&](int s) {
    const unsigned short* g = xsrc0 + s * BK;
    char* lb = smem + XOFF + (s & 1) * 16384 + wv * 1024;
    #pragma unroll
    for (int r = 0; r < 4; ++r)
      __builtin_amdgcn_global_load_lds(
          (const __attribute__((address_space(1))) void*)(g + (size_t)r * 64 * IN_DIM),
          (__attribute__((address_space(3))) void*)(lb + r * 4096), 16, 0, 0);
  };
  auto stage_w = [&](int s) {
    __builtin_amdgcn_global_load_lds(
        (const __attribute__((address_space(1))) void*)(wsrc0 + s * BK),
        (__attribute__((address_space(3))) void*)(smem + WOFF + (s & 3) * 4096 + wv * 1024),
        16, 0, 0);
  };
  auto dq8 = [&](int4 a, int4 b, float sc, float zs) -> bf16x8 {
    bf16x8 r;
    r[0] = (__bf16)((float)a.x * sc - zs);
    r[1] = (__bf16)((float)a.y * sc - zs);
    r[2] = (__bf16)((float)a.z * sc - zs);
    r[3] = (__bf16)((float)a.w * sc - zs);
    r[4] = (__bf16)((float)b.x * sc - zs);
    r[5] = (__bf16)((float)b.y * sc - zs);
    r[6] = (__bf16)((float)b.z * sc - zs);
    r[7] = (__bf16)((float)b.w * sc - zs);
    return r;
  };
  auto rdsc = [&](int tl, int j, float& sc, float& zs) {
    int idx = (tl * 32 + j * 16 + l15) * 4;
    sc = *(const float*)(smem + SCOFF + idx);
    zs = *(const float*)(smem + ZSOFF + idx);
  };
  auto compute = [&](const char* xb, const char* wb,
                     float sc0, float zs0, float sc1, float zs1) {
    bf16x8 a[4];
    #pragma unroll
    for (int i = 0; i < 4; ++i) {
      int row = wv * 64 + i * 16 + l15;
      a[i] = *(const bf16x8*)(xb + row * 64 + (g4 ^ (row & 3)) * 16);
    }
    int c0 = l15, c1 = 16 + l15;
    const char* b0p = wb + c0 * 128;
    const char* b1p = wb + c1 * 128;
    int4 w0 = *(const int4*)(b0p + ((2 * g4) ^ (c0 & 7)) * 16);
    int4 w1 = *(const int4*)(b0p + ((2 * g4 + 1) ^ (c0 & 7)) * 16);
    int4 v0 = *(const int4*)(b1p + ((2 * g4) ^ (c1 & 7)) * 16);
    int4 v1 = *(const int4*)(b1p + ((2 * g4 + 1) ^ (c1 & 7)) * 16);
    bf16x8 b0 = dq8(w0, w1, sc0, zs0);
    bf16x8 b1 = dq8(v0, v1, sc1, zs1);
    #pragma unroll
    for (int i = 0; i < 4; ++i) {
      acc[i][0] = __builtin_amdgcn_mfma_f32_16x16x32_bf16(a[i], b0, acc[i][0], 0, 0, 0);
      acc[i][1] = __builtin_amdgcn_mfma_f32_16x16x32_bf16(a[i], b1, acc[i][1], 0, 0, 0);
    }
  };

  // ---- prologue: scales -> LDS; prime X(0), W(0..2)
  #pragma unroll
  for (int r = 0; r < 2; ++r) {
    int p = t + r * 256;               // 0..511: tile=p>>5, col=p&31
    float s_ = sb[(size_t)(p >> 5) * OUT_DIM + (p & 31)];
    float z_ = zb[(size_t)(p >> 5) * OUT_DIM + (p & 31)];
    *(float*)(smem + SCOFF + p * 4) = s_;
    *(float*)(smem + ZSOFF + p * 4) = z_ * s_;
  }
  __syncthreads();                     // scales visible (one-time full drain)
  stage_x(0);
  stage_w(0); stage_w(1); stage_w(2);
  __builtin_amdgcn_sched_barrier(0);
  asm volatile("s_waitcnt vmcnt(2)");  // X0+W0 done; W1,W2 in flight
  __builtin_amdgcn_sched_barrier(0);
  __builtin_amdgcn_s_barrier();

  // ---- main loop: step s consumes xbuf[s&1], wbuf[s&3];
  // issues X(s+1), W(s+3); vmcnt(1) leaves exactly W(s+3) in flight.
  #pragma unroll 1
  for (int it = 0; it < 15; ++it) {
    float sc0, zs0, sc1, zs1;
    rdsc(it, 0, sc0, zs0);
    rdsc(it, 1, sc1, zs1);
    #pragma unroll
    for (int d = 0; d < 4; ++d) {
      const int s = it * 4 + d;
      stage_x(s + 1);
      stage_w(s + 3);
      compute(smem + XOFF + (d & 1) * 16384, smem + WOFF + d * 4096,
              sc0, zs0, sc1, zs1);
      __builtin_amdgcn_sched_barrier(0);
      asm volatile("s_waitcnt vmcnt(1)");
      __builtin_amdgcn_sched_barrier(0);
      __builtin_amdgcn_s_barrier();
    }
  }
  // ---- tail: s = 60..63 (tl = 15)
  {
    float sc0, zs0, sc1, zs1;
    rdsc(15, 0, sc0, zs0);
    rdsc(15, 1, sc1, zs1);
    // s=60
    stage_x(61); stage_w(63);
    compute(smem + XOFF + 0, smem + WOFF + 0, sc0, zs0, sc1, zs1);
    __builtin_amdgcn_sched_barrier(0);
    asm volatile("s_waitcnt vmcnt(1)");
    __builtin_amdgcn_sched_barrier(0);
    __builtin_amdgcn_s_barrier();
    // s=61
    stage_x(62);
    compute(smem + XOFF + 16384, smem + WOFF + 4096, sc0, zs0, sc1, zs1);
    __builtin_amdgcn_sched_barrier(0);
    asm volatile("s_waitcnt vmcnt(0)");
    __builtin_amdgcn_sched_barrier(0);
    __builtin_amdgcn_s_barrier();
    // s=62
    stage_x(63);
    compute(smem + XOFF + 0, smem + WOFF + 8192, sc0, zs0, sc1, zs1);
    __builtin_amdgcn_sched_barrier(0);
    asm volatile("s_waitcnt vmcnt(0)");
    __builtin_amdgcn_sched_barrier(0);
    __builtin_amdgcn_s_barrier();
    // s=63
    compute(smem + XOFF + 16384, smem + WOFF + 12288, sc0, zs0, sc1, zs1);
  }

  // ---- epilogue: C/D mapping col=lane&15, row=(lane>>4)*4+reg
  if (use_atomic) {
    #pragma unroll
    for (int i = 0; i < 4; ++i) {
      int row0 = wv * 64 + i * 16 + g4 * 4;
      #pragma unroll
      for (int j = 0; j < 2; ++j) {
        int col = n0 + j * 16 + l15;
        #pragma unroll
        for (int r = 0; r < 4; ++r)
          atomicAdd(&outp[(size_t)(row0 + r) * OUT_DIM + col], acc[i][j][r]);
      }
    }
  } else {
    float* pp = outp + (size_t)kh * ((size_t)BDIM * OUT_DIM);
    #pragma unroll
    for (int i = 0; i < 4; ++i) {
      int row0 = wv * 64 + i * 16 + g4 * 4;
      #pragma unroll
      for (int j = 0; j < 2; ++j) {
        int col = n0 + j * 16 + l15;
        #pragma unroll
        for (int r = 0; r < 4; ++r)
          pp[(size_t)(row0 + r) * OUT_DIM + col] = acc[i][j][r];
      }
    }
  }
}

// ---------------- reduce: out = sum of 4 partials (bias folded in kh=0) ----
__global__ void reduce_k(const float* __restrict__ part,
                         float* __restrict__ out) {
  int i4 = blockIdx.x * blockDim.x + threadIdx.x;   // 0..524287
  size_t off = (size_t)i4 * 4;
  const size_t S = (size_t)BDIM * OUT_DIM;
  float4 p0 = *(const float4*)(part + off);
  float4 p1 = *(const float4*)(part + off + S);
  float4 p2 = *(const float4*)(part + off + 2 * S);
  float4 p3 = *(const float4*)(part + off + 3 * S);
  float4 r;
  r.x = p0.x + p1.x + p2.x + p3.x;
  r.y = p0.y + p1.y + p2.y + p3.y;
  r.z = p0.z + p1.z + p2.z + p3.z;
  r.w = p0.w + p1.w + p2.w + p3.w;
  *(float4*)(out + off) = r;
}

extern "C" void kernel_launch(void* const* d_in, const int* in_sizes, int n_in,
                              void* d_out, int out_size, void* d_ws, size_t ws_size,
                              hipStream_t stream) {
  const float* x   = (const float*)d_in[0];
  const int* Whq   = (const int*)d_in[1];
  const int* Wlq   = (const int*)d_in[2];
  const float* sh  = (const float*)d_in[3];
  const float* zh  = (const float*)d_in[4];
  const float* sl  = (const float*)d_in[5];
  const float* zl  = (const float*)d_in[6];
  const float* bias = (const float*)d_in[7];
  const int* ci    = (const int*)d_in[8];
  float* out = (float*)d_out;

  unsigned short* xp = (unsigned short*)d_ws;
  const size_t XP_BYTES = (size_t)BDIM * IN_DIM * 2;                  // 4MB
  const size_t PART_BYTES = (size_t)KSPLIT * BDIM * OUT_DIM * 4;      // 32MB
  bool have_ws = ws_size >= XP_BYTES + PART_BYTES;

  gather_k<<<dim3(2048), dim3(256), 0, stream>>>(x, ci, xp);

  dim3 gg(KSPLIT * (OUT_DIM / BN));   // 1024 linear, swizzled in-kernel
  if (have_ws) {
    float* part = (float*)((char*)d_ws + XP_BYTES);
    gemm_k<<<gg, dim3(256), 0, stream>>>(xp, Whq, Wlq, sh, zh, sl, zl, bias, part, 0);
    reduce_k<<<dim3(2048), dim3(256), 0, stream>>>(part, out);
  } else {
    hipMemsetAsync(d_out, 0, (size_t)out_size * sizeof(float), stream);
    gemm_k<<<gg, dim3(256), 0, stream>>>(xp, Whq, Wlq, sh, zh, sl, zl, bias, out, 1);
  }
}

// Round 6
// 462.119 us; speedup vs baseline: 1.0968x; 1.0968x over previous
//
#include <hip/hip_runtime.h>
#include <stdint.h>

// CPRLinear: out = x[:, ci] @ dequant(W).T + bias
// B=256, IN=OUT=8192; W_high (8192x2048 int32, tile 128), W_low (8192x6144).
// R6: barrier-gated traffic = W stream only (4KB/block/step via global_load_lds,
// ring-4). A-operand in reg dbuf from global (compiler-counted vmcnt, issued
// A-first so A(s)-drain retires W(s+1) => no explicit full drain ever; W(s+2),
// W(s+3) stay in flight across the barrier). LDS 20KB, ~100 VGPR, 4 blocks/CU.

#define IN_DIM 8192
#define OUT_DIM 8192
#define BDIM 256
#define NH 2048
#define NL 6144
#define BN 32
#define BK 32
#define KSPLIT 4
#define KSEG 2048          // IN_DIM / KSPLIT
#define NSTEP 64           // KSEG / BK
#define NT 16              // scale tiles per segment

// LDS (20KB): W ring 4 x 4096 @0; SC @16384; ZS @18432
#define WOFF 0
#define SCOFF 16384
#define ZSOFF 18432

typedef __bf16 bf16x8 __attribute__((ext_vector_type(8)));
typedef float f32x4 __attribute__((ext_vector_type(4)));

__device__ __forceinline__ unsigned short bfbits(float f) {
  union { float f; unsigned int u; } v; v.f = f;
  unsigned int u = v.u;
  u += 0x7fffu + ((u >> 16) & 1u);   // RNE
  return (unsigned short)(u >> 16);
}
__device__ __forceinline__ unsigned int pk2(float a, float b) {
  return (unsigned int)bfbits(a) | ((unsigned int)bfbits(b) << 16);
}

// ---------------- gather + bf16 convert: xp[b][k] = bf16(x[b][ci[k]]) ------
__global__ void gather_k(const float* __restrict__ x,
                         const int* __restrict__ ci,
                         unsigned short* __restrict__ xp) {
  int i4 = blockIdx.x * blockDim.x + threadIdx.x;   // 0..524287
  int b = i4 >> 11;                                  // row (2048 quads/row)
  int k4 = (i4 & 2047) << 2;
  int4 c = *(const int4*)(ci + k4);
  const float* xr = x + (size_t)b * IN_DIM;
  uint2 st;
  st.x = pk2(xr[c.x], xr[c.y]);
  st.y = pk2(xr[c.z], xr[c.w]);
  *(uint2*)(xp + (size_t)b * IN_DIM + k4) = st;
}

// ---------------- GEMM ----------------------------------------------------
// A-load: aF[slot][i], lane reads row wv*64+i*16+l15, k = s*32 + g4*8 (16B).
#define ALOAD(ASLOT, S) { \
  _Pragma("unroll") \
  for (int i = 0; i < 4; ++i) \
    aF[ASLOT][i] = *(const bf16x8*)(xA + (size_t)i * 16 * IN_DIM + (S) * BK); }

// W-stage: thread t -> col t>>3, chunk t&7 (16B), linear LDS dest,
// source chunk pre-swizzled ^(col&7).
#define WSTAGE(WSLOT, S) \
  __builtin_amdgcn_global_load_lds( \
      (const __attribute__((address_space(1))) void*)(wsrc + (S) * BK), \
      (__attribute__((address_space(3))) void*)(smem + WOFF + (WSLOT) * 4096 + wv * 1024), \
      16, 0, 0);

#define SCLOAD(TL) { \
  sc0 = *(const float*)(smem + SCOFF + ((TL) * 32 + l15) * 4); \
  zs0 = *(const float*)(smem + ZSOFF + ((TL) * 32 + l15) * 4); \
  sc1 = *(const float*)(smem + SCOFF + ((TL) * 32 + 16 + l15) * 4); \
  zs1 = *(const float*)(smem + ZSOFF + ((TL) * 32 + 16 + l15) * 4); }

#define COMP(WSLOT, ASLOT) { \
  const char* wb = smem + WOFF + (WSLOT) * 4096 + l15 * 128; \
  int4 w0 = *(const int4*)(wb + wx0); \
  int4 w1 = *(const int4*)(wb + wx1); \
  int4 v0 = *(const int4*)(wb + 2048 + wx0); \
  int4 v1 = *(const int4*)(wb + 2048 + wx1); \
  bf16x8 b0 = dq8(w0, w1, sc0, zs0); \
  bf16x8 b1 = dq8(v0, v1, sc1, zs1); \
  _Pragma("unroll") \
  for (int i = 0; i < 4; ++i) { \
    acc[i][0] = __builtin_amdgcn_mfma_f32_16x16x32_bf16(aF[ASLOT][i], b0, acc[i][0], 0, 0, 0); \
    acc[i][1] = __builtin_amdgcn_mfma_f32_16x16x32_bf16(aF[ASLOT][i], b1, acc[i][1], 0, 0, 0); \
  } }

#define BARSEQ(N) \
  __builtin_amdgcn_sched_barrier(0); \
  asm volatile("s_waitcnt vmcnt(" #N ")"); \
  __builtin_amdgcn_sched_barrier(0); \
  __builtin_amdgcn_s_barrier();

__global__ __launch_bounds__(256, 4)
void gemm_k(const unsigned short* __restrict__ xp,
            const int* __restrict__ Whq, const int* __restrict__ Wlq,
            const float* __restrict__ sh, const float* __restrict__ zh,
            const float* __restrict__ sl, const float* __restrict__ zl,
            const float* __restrict__ bias,
            float* __restrict__ outp,
            int use_atomic)
{
  __shared__ char smem[20480];
  const int t = threadIdx.x;
  const int lane = t & 63;
  const int wv = t >> 6;
  const int l15 = lane & 15;
  const int g4 = lane >> 4;

  // XCD-bijective swizzle (1024 % 8 == 0), kh-major decode: each XCD's 128
  // blocks share one 1MB X-slice (L2-resident).
  const int swz = (blockIdx.x & 7) * 128 + (blockIdx.x >> 3);
  const int kh = swz >> 8;          // 0..3
  const int n0 = (swz & 255) * BN;  // 0..8160
  const bool hi = (kh == 0);        // KSEG==NH: kh0 all-high, else all-low

  const int wcol = t >> 3;          // 0..31
  const int* wsrc = (hi ? Whq + (size_t)(n0 + wcol) * NH
                        : Wlq + (size_t)(n0 + wcol) * NL + (size_t)(kh - 1) * KSEG)
                    + ((t & 7) ^ (wcol & 7)) * 4;
  const float* sbase = (hi ? sh : sl + (size_t)(kh - 1) * NT * OUT_DIM) + n0;
  const float* zbase = (hi ? zh : zl + (size_t)(kh - 1) * NT * OUT_DIM) + n0;

  const unsigned short* xA = xp + (size_t)(wv * 64 + l15) * IN_DIM
                                + (size_t)kh * KSEG + g4 * 8;

  const int wx0 = ((2 * g4) ^ (l15 & 7)) * 16;       // W read chunk swizzle
  const int wx1 = ((2 * g4 + 1) ^ (l15 & 7)) * 16;

  auto dq8 = [&](int4 a, int4 b, float sc, float zs) -> bf16x8 {
    bf16x8 r;
    r[0] = (__bf16)((float)a.x * sc - zs);
    r[1] = (__bf16)((float)a.y * sc - zs);
    r[2] = (__bf16)((float)a.z * sc - zs);
    r[3] = (__bf16)((float)a.w * sc - zs);
    r[4] = (__bf16)((float)b.x * sc - zs);
    r[5] = (__bf16)((float)b.y * sc - zs);
    r[6] = (__bf16)((float)b.z * sc - zs);
    r[7] = (__bf16)((float)b.w * sc - zs);
    return r;
  };

  // ---- scales -> LDS; bias -> acc (all drained before pipeline priming)
  #pragma unroll
  for (int r = 0; r < 2; ++r) {
    int p = t + r * 256;               // (tile,col): tile=p>>5, col=p&31
    float s_ = sbase[(size_t)(p >> 5) * OUT_DIM + (p & 31)];
    float z_ = zbase[(size_t)(p >> 5) * OUT_DIM + (p & 31)];
    *(float*)(smem + SCOFF + p * 4) = s_;
    *(float*)(smem + ZSOFF + p * 4) = z_ * s_;
  }
  f32x4 acc[4][2];
  {
    float bv0 = hi ? bias[n0 + l15] : 0.f;
    float bv1 = hi ? bias[n0 + 16 + l15] : 0.f;
    #pragma unroll
    for (int i = 0; i < 4; ++i) {
      acc[i][0][0] = bv0; acc[i][0][1] = bv0; acc[i][0][2] = bv0; acc[i][0][3] = bv0;
      acc[i][1][0] = bv1; acc[i][1][1] = bv1; acc[i][1][2] = bv1; acc[i][1][3] = bv1;
    }
  }
  __builtin_amdgcn_sched_barrier(0);   // vmcnt clean past this point

  // ---- prime: A(0) regs; W(0..2) in flight; queue [A0^4, W0, W1, W2]
  bf16x8 aF[2][4];
  ALOAD(0, 0);
  WSTAGE(0, 0); WSTAGE(1, 1); WSTAGE(2, 2);
  __builtin_amdgcn_sched_barrier(0);
  asm volatile("s_waitcnt vmcnt(2) lgkmcnt(0)");   // A0+W0 done; W1,W2 fly
  __builtin_amdgcn_sched_barrier(0);
  __builtin_amdgcn_s_barrier();

  // ---- main loop, unroll 4. Step s: issue A(s+1) then W(s+3); compute(s).
  // Compiler's A(s)-use wait = vmcnt(6) -> also retires W(s+1) (older) before
  // the barrier; W(s+2), W(s+3) remain in flight across it.
  float sc0, zs0, sc1, zs1;
  #pragma unroll 1
  for (int base = 0; base < 60; base += 4) {
    SCLOAD(base >> 2);
    // k=0
    ALOAD(1, base + 1); WSTAGE(3, base + 3);
    __builtin_amdgcn_sched_barrier(0);
    COMP(0, 0);
    BARSEQ(6)
    // k=1
    ALOAD(0, base + 2); WSTAGE(0, base + 4);
    __builtin_amdgcn_sched_barrier(0);
    COMP(1, 1);
    BARSEQ(6)
    // k=2
    ALOAD(1, base + 3); WSTAGE(1, base + 5);
    __builtin_amdgcn_sched_barrier(0);
    COMP(2, 0);
    BARSEQ(6)
    // k=3
    ALOAD(0, base + 4); WSTAGE(2, base + 6);
    __builtin_amdgcn_sched_barrier(0);
    COMP(3, 1);
    BARSEQ(6)
  }
  // ---- tail: s = 60..63 (tile 15)
  SCLOAD(15);
  // s=60
  ALOAD(1, 61); WSTAGE(3, 63);
  __builtin_amdgcn_sched_barrier(0);
  COMP(0, 0);
  BARSEQ(6)
  // s=61
  ALOAD(0, 62);
  __builtin_amdgcn_sched_barrier(0);
  COMP(1, 1);
  BARSEQ(5)
  // s=62
  ALOAD(1, 63);
  __builtin_amdgcn_sched_barrier(0);
  COMP(2, 0);
  BARSEQ(4)
  // s=63 (all loads drained by compiler waits; no barrier needed)
  COMP(3, 1);

  // ---- epilogue: C/D mapping col=lane&15, row=(lane>>4)*4+reg
  if (use_atomic) {
    #pragma unroll
    for (int i = 0; i < 4; ++i) {
      int row0 = wv * 64 + i * 16 + g4 * 4;
      #pragma unroll
      for (int j = 0; j < 2; ++j) {
        int col = n0 + j * 16 + l15;
        #pragma unroll
        for (int r = 0; r < 4; ++r)
          atomicAdd(&outp[(size_t)(row0 + r) * OUT_DIM + col], acc[i][j][r]);
      }
    }
  } else {
    float* pp = outp + (size_t)kh * ((size_t)BDIM * OUT_DIM);
    #pragma unroll
    for (int i = 0; i < 4; ++i) {
      int row0 = wv * 64 + i * 16 + g4 * 4;
      #pragma unroll
      for (int j = 0; j < 2; ++j) {
        int col = n0 + j * 16 + l15;
        #pragma unroll
        for (int r = 0; r < 4; ++r)
          pp[(size_t)(row0 + r) * OUT_DIM + col] = acc[i][j][r];
      }
    }
  }
}

// ---------------- reduce: out = sum of 4 partials (bias folded in kh=0) ----
__global__ void reduce_k(const float* __restrict__ part,
                         float* __restrict__ out) {
  int i4 = blockIdx.x * blockDim.x + threadIdx.x;   // 0..524287
  size_t off = (size_t)i4 * 4;
  const size_t S = (size_t)BDIM * OUT_DIM;
  float4 p0 = *(const float4*)(part + off);
  float4 p1 = *(const float4*)(part + off + S);
  float4 p2 = *(const float4*)(part + off + 2 * S);
  float4 p3 = *(const float4*)(part + off + 3 * S);
  float4 r;
  r.x = p0.x + p1.x + p2.x + p3.x;
  r.y = p0.y + p1.y + p2.y + p3.y;
  r.z = p0.z + p1.z + p2.z + p3.z;
  r.w = p0.w + p1.w + p2.w + p3.w;
  *(float4*)(out + off) = r;
}

extern "C" void kernel_launch(void* const* d_in, const int* in_sizes, int n_in,
                              void* d_out, int out_size, void* d_ws, size_t ws_size,
                              hipStream_t stream) {
  const float* x   = (const float*)d_in[0];
  const int* Whq   = (const int*)d_in[1];
  const int* Wlq   = (const int*)d_in[2];
  const float* sh  = (const float*)d_in[3];
  const float* zh  = (const float*)d_in[4];
  const float* sl  = (const float*)d_in[5];
  const float* zl  = (const float*)d_in[6];
  const float* bias = (const float*)d_in[7];
  const int* ci    = (const int*)d_in[8];
  float* out = (float*)d_out;

  unsigned short* xp = (unsigned short*)d_ws;
  const size_t XP_BYTES = (size_t)BDIM * IN_DIM * 2;                  // 4MB
  const size_t PART_BYTES = (size_t)KSPLIT * BDIM * OUT_DIM * 4;      // 32MB
  bool have_ws = ws_size >= XP_BYTES + PART_BYTES;

  gather_k<<<dim3(2048), dim3(256), 0, stream>>>(x, ci, xp);

  dim3 gg(KSPLIT * (OUT_DIM / BN));   // 1024 linear, swizzled in-kernel
  if (have_ws) {
    float* part = (float*)((char*)d_ws + XP_BYTES);
    gemm_k<<<gg, dim3(256), 0, stream>>>(xp, Whq, Wlq, sh, zh, sl, zl, bias, part, 0);
    reduce_k<<<dim3(2048), dim3(256), 0, stream>>>(part, out);
  } else {
    hipMemsetAsync(d_out, 0, (size_t)out_size * sizeof(float), stream);
    gemm_k<<<gg, dim3(256), 0, stream>>>(xp, Whq, Wlq, sh, zh, sl, zl, bias, out, 1);
  }
}

// Round 7
// 400.546 us; speedup vs baseline: 1.2654x; 1.1537x over previous
//
#include <hip/hip_runtime.h>
#include <stdint.h>

// CPRLinear: out = x[:, ci] @ dequant(W).T + bias
// B=256, IN=OUT=8192; W_high (8192x2048 int32, tile 128), W_low (8192x6144).
// R7: all 2-phase schedules pinned at ~6 TB/s aggregate delivery (R2-R6).
// -> m201-style 8-phase counted-vmcnt structure + BN=256 (cuts aggregate
// bytes 1.3GB -> ~0.5GB). 512 thr / 8 waves (2Mx4N), wave=128x64, BK=32.
// W staged RAW int32 via global_load_lds ring-3 (2 tiles ahead, vmcnt(4)
// once per tile, never 0 in loop); X bf16 dbuf; dequant fused into the
// LDS->reg B-frag read. KSPLIT=8, kh = XCD-local. LDS 144KB, ~210 VGPR.

#define IN_DIM 8192
#define OUT_DIM 8192
#define BDIM 256
#define NH 2048
#define NL 6144
#define BN 256
#define BK 32
#define KSPLIT 8
#define KSEG 1024          // IN_DIM / KSPLIT
#define NTIL 32            // K-tiles per segment (KSEG/BK)
#define NT 8               // scale tiles per segment (KSEG/128)

// LDS (144KB): X dbuf 2x16384 @0; W ring-3 3x32768 @32768; SC/ZS @131072
#define XOFF 0
#define WOFF 32768
#define SCOFF 131072
#define ZSOFF 139264

typedef __bf16 bf16x8 __attribute__((ext_vector_type(8)));
typedef float f32x4 __attribute__((ext_vector_type(4)));

__device__ __forceinline__ unsigned short bfbits(float f) {
  union { float f; unsigned int u; } v; v.f = f;
  unsigned int u = v.u;
  u += 0x7fffu + ((u >> 16) & 1u);   // RNE
  return (unsigned short)(u >> 16);
}
__device__ __forceinline__ unsigned int pk2(float a, float b) {
  return (unsigned int)bfbits(a) | ((unsigned int)bfbits(b) << 16);
}

// ---------------- gather + bf16 convert: xp[b][k] = bf16(x[b][ci[k]]) ------
__global__ void gather_k(const float* __restrict__ x,
                         const int* __restrict__ ci,
                         unsigned short* __restrict__ xp) {
  int i4 = blockIdx.x * blockDim.x + threadIdx.x;   // 0..524287
  int b = i4 >> 11;                                  // row (2048 quads/row)
  int k4 = (i4 & 2047) << 2;
  int4 c = *(const int4*)(ci + k4);
  const float* xr = x + (size_t)b * IN_DIM;
  uint2 st;
  st.x = pk2(xr[c.x], xr[c.y]);
  st.y = pk2(xr[c.z], xr[c.w]);
  *(uint2*)(xp + (size_t)b * IN_DIM + k4) = st;
}

// ---------------- GEMM ----------------------------------------------------
#define PH_OPEN \
  __builtin_amdgcn_sched_barrier(0); \
  __builtin_amdgcn_s_barrier(); \
  __builtin_amdgcn_sched_barrier(0)

#define STAGE_X(S) { \
  _Pragma("unroll") \
  for (int q_ = 0; q_ < 2; ++q_) \
    __builtin_amdgcn_global_load_lds( \
      (const __attribute__((address_space(1))) void*)(xsrc + (size_t)q_ * 128 * IN_DIM * 2 + (S) * 64), \
      (__attribute__((address_space(3))) void*)(smem + XOFF + ((S) & 1) * 16384 + q_ * 8192 + wv * 1024), \
      16, 0, 0); \
}

#define STAGE_WQ(S, BUF, Q) \
  __builtin_amdgcn_global_load_lds( \
    (const __attribute__((address_space(1))) void*)(wsrc + (size_t)(Q) * 64 * ldw + (S) * 32), \
    (__attribute__((address_space(3))) void*)(smem + WOFF + (BUF) * 32768 + (Q) * 8192 + wv * 1024), \
    16, 0, 0);

#define BREAD(WBP, J, U0, U1) { \
  int col_ = wc64 + (J) * 16 + l15; \
  const char* bp_ = (WBP) + col_ * 128; \
  U0 = *(const int4*)(bp_ + (((2 * g4) ^ (col_ & 7)) * 16)); \
  U1 = *(const int4*)(bp_ + (((2 * g4 + 1) ^ (col_ & 7)) * 16)); \
}

#define MFMA8(BJ, J) { \
  _Pragma("unroll") \
  for (int i_ = 0; i_ < 8; ++i_) \
    acc[i_][J] = __builtin_amdgcn_mfma_f32_16x16x32_bf16(aF[i_], BJ, acc[i_][J], 0, 0, 0); \
}

// One K-tile = 4 phases; W(t+2) issued P1/P2, X(t+1) issued P0; VMST once.
#define TILE(T, ISSX, ISSW, VMST) { \
  const int xb_ = (T) & 1, wb_ = (T) % 3, wb2_ = ((T) + 2) % 3; \
  const char* xbp_ = smem + XOFF + xb_ * 16384; \
  const char* wbp_ = smem + WOFF + wb_ * 32768; \
  const int tl_ = (T) >> 2; \
  /* P0: A-frags + scales + B0 reads; issue X(t+1) */ \
  bf16x8 aF[8]; \
  _Pragma("unroll") \
  for (int i_ = 0; i_ < 8; ++i_) { \
    int row_ = wr128 + i_ * 16 + l15; \
    aF[i_] = *(const bf16x8*)(xbp_ + row_ * 64 + ((g4 ^ (row_ & 3)) * 16)); \
  } \
  float scf_[4], zsf_[4]; \
  _Pragma("unroll") \
  for (int j_ = 0; j_ < 4; ++j_) { \
    int sidx_ = (tl_ * 256 + wc64 + j_ * 16 + l15) * 4; \
    scf_[j_] = *(const float*)(smem + SCOFF + sidx_); \
    zsf_[j_] = *(const float*)(smem + ZSOFF + sidx_); \
  } \
  int4 u0_, u1_; \
  BREAD(wbp_, 0, u0_, u1_); \
  if (ISSX) STAGE_X((T) + 1); \
  PH_OPEN; \
  __builtin_amdgcn_s_setprio(1); \
  { bf16x8 b_ = dq8(u0_, u1_, scf_[0], zsf_[0]); MFMA8(b_, 0); } \
  __builtin_amdgcn_s_setprio(0); \
  PH_OPEN; \
  /* P1 */ \
  BREAD(wbp_, 1, u0_, u1_); \
  if (ISSW) { STAGE_WQ((T) + 2, wb2_, 0); STAGE_WQ((T) + 2, wb2_, 1); } \
  PH_OPEN; \
  __builtin_amdgcn_s_setprio(1); \
  { bf16x8 b_ = dq8(u0_, u1_, scf_[1], zsf_[1]); MFMA8(b_, 1); } \
  __builtin_amdgcn_s_setprio(0); \
  PH_OPEN; \
  /* P2 */ \
  BREAD(wbp_, 2, u0_, u1_); \
  if (ISSW) { STAGE_WQ((T) + 2, wb2_, 2); STAGE_WQ((T) + 2, wb2_, 3); } \
  PH_OPEN; \
  __builtin_amdgcn_s_setprio(1); \
  { bf16x8 b_ = dq8(u0_, u1_, scf_[2], zsf_[2]); MFMA8(b_, 2); } \
  __builtin_amdgcn_s_setprio(0); \
  PH_OPEN; \
  /* P3 + counted vmcnt (never 0 in main loop) */ \
  BREAD(wbp_, 3, u0_, u1_); \
  PH_OPEN; \
  __builtin_amdgcn_s_setprio(1); \
  { bf16x8 b_ = dq8(u0_, u1_, scf_[3], zsf_[3]); MFMA8(b_, 3); } \
  __builtin_amdgcn_s_setprio(0); \
  __builtin_amdgcn_sched_barrier(0); \
  VMST; \
  __builtin_amdgcn_sched_barrier(0); \
  __builtin_amdgcn_s_barrier(); \
  __builtin_amdgcn_sched_barrier(0); \
}

__global__ __launch_bounds__(512, 1)
void gemm_k(const unsigned short* __restrict__ xp,
            const int* __restrict__ Whq, const int* __restrict__ Wlq,
            const float* __restrict__ sh, const float* __restrict__ zh,
            const float* __restrict__ sl, const float* __restrict__ zl,
            const float* __restrict__ bias,
            float* __restrict__ outp,
            int use_atomic)
{
  __shared__ __attribute__((aligned(16))) char smem[147456];
  const int t = threadIdx.x;
  const int lane = t & 63;
  const int wv = t >> 6;            // 0..7
  const int wr128 = (wv >> 2) * 128;
  const int wc64 = (wv & 3) * 64;
  const int l15 = lane & 15;
  const int g4 = lane >> 4;

  // kh = XCD-local (dispatch round-robins bid%8): 32 blocks/XCD share one
  // 512KB X-slice (L2-resident); W rows distinct per block.
  const int kh = blockIdx.x & 7;
  const int n0 = (blockIdx.x >> 3) * BN;
  const bool hi = (kh < 2);         // kh 0,1 = high region; 2..7 = low

  // X staging addr: row = q*128 + (t>>2), src chunk = (t&3)^(row&3)
  const char* xsrc = (const char*)xp + (size_t)(t >> 2) * (IN_DIM * 2)
                   + (size_t)kh * KSEG * 2 + (((t & 3) ^ ((t >> 2) & 3)) * 16);
  // W staging addr: col = q*64 + (t>>3), chunk = (t&7)^(col&7) (16B units)
  const int wcol0 = t >> 3;
  const int ldw = hi ? NH : NL;
  const int* wsrc = (hi ? Whq + (size_t)kh * KSEG : Wlq + (size_t)(kh - 2) * KSEG)
                  + (size_t)(n0 + wcol0) * ldw + ((t & 7) ^ (wcol0 & 7)) * 4;

  const float* sbase = (hi ? sh + (size_t)kh * NT * OUT_DIM
                           : sl + (size_t)(kh - 2) * NT * OUT_DIM) + n0;
  const float* zbase = (hi ? zh + (size_t)kh * NT * OUT_DIM
                           : zl + (size_t)(kh - 2) * NT * OUT_DIM) + n0;

  auto dq8 = [&](int4 a, int4 b, float sc, float zs) -> bf16x8 {
    bf16x8 r;
    r[0] = (__bf16)((float)a.x * sc - zs);
    r[1] = (__bf16)((float)a.y * sc - zs);
    r[2] = (__bf16)((float)a.z * sc - zs);
    r[3] = (__bf16)((float)a.w * sc - zs);
    r[4] = (__bf16)((float)b.x * sc - zs);
    r[5] = (__bf16)((float)b.y * sc - zs);
    r[6] = (__bf16)((float)b.z * sc - zs);
    r[7] = (__bf16)((float)b.w * sc - zs);
    return r;
  };

  // ---- accumulators (bias folded into kh==0)
  f32x4 acc[8][4];
  #pragma unroll
  for (int j = 0; j < 4; ++j) {
    float bv = (kh == 0) ? bias[n0 + wc64 + j * 16 + l15] : 0.f;
    #pragma unroll
    for (int i = 0; i < 8; ++i) {
      acc[i][j][0] = bv; acc[i][j][1] = bv; acc[i][j][2] = bv; acc[i][j][3] = bv;
    }
  }

  // ---- prologue: scales -> LDS; prime X(0), W(0), W(1); one full drain
  #pragma unroll
  for (int r = 0; r < 4; ++r) {
    int p = t + r * 512;             // (tile,col): tile=p>>8, col=p&255
    float s_ = sbase[(size_t)(p >> 8) * OUT_DIM + (p & 255)];
    float z_ = zbase[(size_t)(p >> 8) * OUT_DIM + (p & 255)];
    *(float*)(smem + SCOFF + p * 4) = s_;
    *(float*)(smem + ZSOFF + p * 4) = z_ * s_;
  }
  STAGE_X(0);
  STAGE_WQ(0, 0, 0); STAGE_WQ(0, 0, 1); STAGE_WQ(0, 0, 2); STAGE_WQ(0, 0, 3);
  STAGE_WQ(1, 1, 0); STAGE_WQ(1, 1, 1); STAGE_WQ(1, 1, 2); STAGE_WQ(1, 1, 3);
  __syncthreads();

  // ---- main loop: ledger (steady t): start [W(t+1)x4]; +X(t+1)x2 (P0),
  // +W(t+2)x4 (P1,P2); end vmcnt(4) retires X(t+1)&older, leaves W(t+2)x4.
  #pragma unroll 1
  for (int tt = 0; tt < 30; ++tt) {
    TILE(tt, true, true, asm volatile("s_waitcnt vmcnt(4)"));
  }
  TILE(30, true, false, asm volatile("s_waitcnt vmcnt(0)"));
  TILE(31, false, false, (void)0);

  // ---- epilogue: C/D mapping col=lane&15, row=(lane>>4)*4+reg
  if (use_atomic) {
    #pragma unroll
    for (int i = 0; i < 8; ++i) {
      int row0 = wr128 + i * 16 + g4 * 4;
      #pragma unroll
      for (int j = 0; j < 4; ++j) {
        int col = n0 + wc64 + j * 16 + l15;
        #pragma unroll
        for (int r = 0; r < 4; ++r)
          atomicAdd(&outp[(size_t)(row0 + r) * OUT_DIM + col], acc[i][j][r]);
      }
    }
  } else {
    float* pp = outp + (size_t)kh * ((size_t)BDIM * OUT_DIM);
    #pragma unroll
    for (int i = 0; i < 8; ++i) {
      int row0 = wr128 + i * 16 + g4 * 4;
      #pragma unroll
      for (int j = 0; j < 4; ++j) {
        int col = n0 + wc64 + j * 16 + l15;
        #pragma unroll
        for (int r = 0; r < 4; ++r)
          pp[(size_t)(row0 + r) * OUT_DIM + col] = acc[i][j][r];
      }
    }
  }
}

// ---------------- reduce: out = sum of NS partials (bias folded in kh=0) ---
template<int NS>
__global__ void reduce_k(const float* __restrict__ part,
                         float* __restrict__ out) {
  int i4 = blockIdx.x * blockDim.x + threadIdx.x;   // 0..524287
  size_t off = (size_t)i4 * 4;
  const size_t S = (size_t)BDIM * OUT_DIM;
  float4 r = *(const float4*)(part + off);
  #pragma unroll
  for (int k = 1; k < NS; ++k) {
    float4 p = *(const float4*)(part + off + (size_t)k * S);
    r.x += p.x; r.y += p.y; r.z += p.z; r.w += p.w;
  }
  *(float4*)(out + off) = r;
}

extern "C" void kernel_launch(void* const* d_in, const int* in_sizes, int n_in,
                              void* d_out, int out_size, void* d_ws, size_t ws_size,
                              hipStream_t stream) {
  const float* x   = (const float*)d_in[0];
  const int* Whq   = (const int*)d_in[1];
  const int* Wlq   = (const int*)d_in[2];
  const float* sh  = (const float*)d_in[3];
  const float* zh  = (const float*)d_in[4];
  const float* sl  = (const float*)d_in[5];
  const float* zl  = (const float*)d_in[6];
  const float* bias = (const float*)d_in[7];
  const int* ci    = (const int*)d_in[8];
  float* out = (float*)d_out;

  unsigned short* xp = (unsigned short*)d_ws;
  const size_t XP_BYTES = (size_t)BDIM * IN_DIM * 2;                  // 4MB
  const size_t PART_BYTES = (size_t)KSPLIT * BDIM * OUT_DIM * 4;      // 64MB
  bool have_ws = ws_size >= XP_BYTES + PART_BYTES;

  gather_k<<<dim3(2048), dim3(256), 0, stream>>>(x, ci, xp);

  dim3 gg(KSPLIT * (OUT_DIM / BN));   // 256 blocks, kh = bid&7 (XCD-local)
  if (have_ws) {
    float* part = (float*)((char*)d_ws + XP_BYTES);
    gemm_k<<<gg, dim3(512), 0, stream>>>(xp, Whq, Wlq, sh, zh, sl, zl, bias, part, 0);
    reduce_k<KSPLIT><<<dim3(2048), dim3(256), 0, stream>>>(part, out);
  } else {
    hipMemsetAsync(d_out, 0, (size_t)out_size * sizeof(float), stream);
    gemm_k<<<gg, dim3(512), 0, stream>>>(xp, Whq, Wlq, sh, zh, sl, zl, bias, out, 1);
  }
}